// Round 14
// baseline (305.470 us; speedup 1.0000x reference)
//
#include <hip/hip_runtime.h>
#include <hip/hip_bf16.h>
#include <math.h>

// B=2 V=3 G=2 NH=8 C=128 CPG=64 CH=16 HPG=4 Hq=Wq=32 D=4 Hk=16 Wk=128 NS=2048
// Hi=Wi=64 SCALE=0.25 OFR=5 EPS=1e-5  RPE 63x255 per head
// All inputs fp32, output fp32 (established R2-R6).
// R14: (1) pre-paired global rpe table gP[8][66][258] -> k_attn stages via
//      flat uint2 memcpy (no div/pack); (2) k_attn inner loop 2-tile slices
//      (S live set 32->8 regs); (3) p_sm stride 42 (write-conflict fix);
//      (4) outproj 512 blocks.

typedef __attribute__((ext_vector_type(8))) short short8;
typedef __attribute__((ext_vector_type(4))) float f32x4;

__device__ __forceinline__ unsigned short f2b(float f){        // fp32 -> bf16 RNE
  unsigned u = __float_as_uint(f);
  return (unsigned short)((u + 0x7FFFu + ((u>>16)&1u)) >> 16);
}
__device__ __forceinline__ unsigned pack2(float lo, float hi){
  return (unsigned)f2b(lo) | ((unsigned)f2b(hi) << 16);
}

__global__ void k_probe(float* __restrict__ out, float code){
  if(blockIdx.x==0 && threadIdx.x==0) out[0] = code;
}

// ---------------------------------------------------------------- K0: offsets + x-transpose + weight prep + rpe pair table
__global__ __launch_bounds__(256) void k_prep_off(
    const float* __restrict__ query, const float* __restrict__ refp,
    const float* __restrict__ w1, const float* __restrict__ b1,
    const float* __restrict__ lng, const float* __restrict__ lnb,
    const float* __restrict__ w2, float* __restrict__ rwo, float* __restrict__ rws,
    const float* __restrict__ x, float* __restrict__ xt,
    const float* __restrict__ k_w, const float* __restrict__ v_w, const float* __restrict__ out_w,
    unsigned short* __restrict__ kw16, unsigned short* __restrict__ vw16, float* __restrict__ ow_t,
    const float* __restrict__ rpe, unsigned* __restrict__ gP){
  __shared__ float t[64][65];
  int bx = blockIdx.x;               // 4693 = 3072 offsets + 768 transpose + 320 wprep + 533 gP
  if(bx < 3072){
    int wid  = bx*4 + (threadIdx.x>>6);
    int lane = threadIdx.x & 63;
    int vi  = wid >> 12;
    int rem = wid & 4095;
    int bg  = rem >> 10;
    int pix = rem & 1023;
    int y = pix >> 5, xq = pix & 31;
    int b = bg >> 1, g = bg & 1;
    float qv = query[(size_t)(b*128 + g*64 + lane)*1024 + pix];
    float h[4]; float s1 = 0.f, s2 = 0.f;
    #pragma unroll
    for(int d=0; d<4; ++d){
      h[d] = qv*w1[vi*256 + lane*4 + d] + b1[vi*256 + lane*4 + d];
      s1 += h[d]; s2 += h[d]*h[d];
    }
    #pragma unroll
    for(int off=1; off<64; off<<=1){ s1 += __shfl_xor(s1, off); s2 += __shfl_xor(s2, off); }
    float mu   = s1 * (1.f/256.f);
    float var  = s2 * (1.f/256.f) - mu*mu;
    float rstd = rsqrtf(fmaxf(var, 0.f) + 1e-5f);
    float po[4] = {0.f,0.f,0.f,0.f};
    #pragma unroll
    for(int d=0; d<4; ++d){
      float hv = (h[d]-mu)*rstd*lng[vi*256+lane*4+d] + lnb[vi*256+lane*4+d];
      hv = 0.5f*hv*(1.f + erff(hv*0.70710678118654752f));   // exact GELU
      #pragma unroll
      for(int o=0; o<4; ++o) po[o] += w2[(vi*4+o)*256 + lane*4 + d] * hv;
    }
    #pragma unroll
    for(int off=1; off<64; off<<=1){
      #pragma unroll
      for(int o=0; o<4; ++o) po[o] += __shfl_xor(po[o], off);
    }
    if(lane == 0){
      int tt = y & 1, hk = y >> 1;
      float rng = tt ? (5.f/127.f) : (5.f/15.f);
      float csc = tt ? 63.5f : 15.5f;
      #pragma unroll
      for(int d=0; d<4; ++d){
        int wk = xq*4 + d;
        float rv = refp[(size_t)(((b*3+vi)*16 + hk)*128 + wk)*2 + (1-tt)];  // [..., ::-1]
        float coord = tanhf(po[d])*rng + rv;
        size_t o2 = ((size_t)(vi*4+bg)*2048 + hk*128 + wk)*2 + tt;
        rwo[o2] = coord;
        rws[o2] = coord * csc;
      }
    }
  } else if(bx < 3840){
    int pb = bx - 3072;
    int iy = pb & 63;
    int o2 = pb >> 6;
    const float* src = x + ((size_t)o2*64)*4096 + (size_t)iy*64;
    int ix = threadIdx.x & 63, cq = threadIdx.x >> 6;
    #pragma unroll
    for(int c0 = 0; c0 < 64; c0 += 4)
      t[c0+cq][ix] = src[(size_t)(c0+cq)*4096 + ix];
    __syncthreads();
    float* dst = xt + (((size_t)o2*64 + iy)*64)*64;
    int c = threadIdx.x & 63, xq = threadIdx.x >> 6;
    #pragma unroll
    for(int x0 = 0; x0 < 64; x0 += 4)
      dst[(size_t)(x0+xq)*64 + c] = t[c][x0+xq];
  } else if(bx < 4160){
    int wb = bx - 3840;              // 320 = 64 kw16 + 64 vw16 + 192 ow_t
    if(wb < 128){
      int i = (wb & 63)*256 + threadIdx.x;
      if(wb < 64) kw16[i] = f2b(k_w[i]);
      else        vw16[i] = f2b(v_w[i]);
    } else {
      int i = (wb-128)*256 + threadIdx.x;
      if(i < 49152){
        int r = i / 384, c = i - r*384;
        ow_t[c*128 + r] = out_w[i];
      }
    }
  } else {
    // gP[nh][iy+2][cc]: vertical bf16 pair (row iy, iy+1), log2-scaled, zero-padded
    int e = (bx - 4160)*256 + threadIdx.x;
    if(e < 136224){                  // 8*66*258
      int nh = e / 17028;
      int r  = e - nh*17028;
      int iy = r / 258 - 2;
      int cc = r - (iy+2)*258;
      int ix = cc - 1;
      const float* rt = rpe + (size_t)nh*16065;
      bool xv = (ix >= 0) && (ix <= 254);
      float lo = (xv && iy   >= 0 && iy   <= 62) ? rt[iy*255 + ix]     : 0.f;
      float hi = (xv && iy+1 >= 0 && iy+1 <= 62) ? rt[(iy+1)*255 + ix] : 0.f;
      gP[e] = pack2(lo*1.44269504f, hi*1.44269504f);
    }
  }
}

// ---------------------------------------------------------------- K1: fused sample + MFMA K/V projection
__global__ __launch_bounds__(256) void k_sampro(
    const float* __restrict__ rwo, const float* __restrict__ xt,
    const unsigned short* __restrict__ kw16, const float* __restrict__ k_b,
    const unsigned short* __restrict__ vw16, const float* __restrict__ v_b,
    unsigned short* __restrict__ k_b16, unsigned short* __restrict__ v_t16){
  __shared__ alignas(16) unsigned short tile[16*136];   // 4352 B bf16 xs tile
  int bx = blockIdx.x;               // 768 = (vi*2+b)*128 + nt
  int nt = bx & 127;
  int r2 = bx >> 7;
  int b = r2 & 1, vi = r2 >> 1;
  int n0 = nt*16;
  int tid = threadIdx.x, wid = tid>>6, lane = tid&63;
  #pragma unroll
  for(int s = 0; s < 8; ++s){        // 32 (n,g) units, 8 per wave
    int u = wid*8 + s;
    int nl = u >> 1, g = u & 1;
    int n = n0 + nl;
    float yn = rwo[((size_t)(vi*4 + b*2 + g)*2048 + n)*2 + 0];
    float xn = rwo[((size_t)(vi*4 + b*2 + g)*2048 + n)*2 + 1];
    float px = (xn + 1.f)*31.5f;
    float py = (yn + 1.f)*31.5f;
    float x0 = floorf(px), y0 = floorf(py);
    float fx = px - x0, fy = py - y0;
    int ix0 = (int)x0, iy0 = (int)y0;
    const float* base = xt + (size_t)((b*3+vi)*2+g)*4096*64;
    float wts[4] = {(1.f-fx)*(1.f-fy), fx*(1.f-fy), (1.f-fx)*fy, fx*fy};
    int ixs[4] = {ix0, ix0+1, ix0, ix0+1};
    int iys[4] = {iy0, iy0, iy0+1, iy0+1};
    float acc = 0.f;
    #pragma unroll
    for(int tp=0; tp<4; ++tp){
      int ix = ixs[tp], iy = iys[tp];
      if(ix>=0 && ix<64 && iy>=0 && iy<64)
        acc += wts[tp] * base[(size_t)((iy<<6)+ix)*64 + lane];
    }
    tile[nl*136 + g*64 + lane] = f2b(acc);
  }
  __syncthreads();
  int c = lane & 15, qd = lane >> 4;
  short8 af[4];                      // A[m=sample n=c][k=chan qd*8+j], 4 x K=32 = 128 ch
  #pragma unroll
  for(int kc=0; kc<4; ++kc)
    af[kc] = *(const short8*)(&tile[c*136 + kc*32 + qd*8]);
  size_t vbbase = (size_t)(vi*16 + b*8)*2048*16;
  #pragma unroll
  for(int half=0; half<2; ++half){
    int nh = wid*2 + half;
    size_t hbase = vbbase + (size_t)nh*2048*16;
    {  // K head: k_b16[n][ch]
      f32x4 C = {0.f,0.f,0.f,0.f};
      #pragma unroll
      for(int kc=0; kc<4; ++kc){
        short8 bf = *(const short8*)(kw16 + (size_t)(nh*16 + c)*128 + kc*32 + qd*8);
        C = __builtin_amdgcn_mfma_f32_16x16x32_bf16(af[kc], bf, C, 0, 0, 0);
      }
      float bias = k_b[nh*16 + c];
      #pragma unroll
      for(int r=0; r<4; ++r)
        k_b16[hbase + (size_t)(n0 + qd*4 + r)*16 + c] = f2b(C[r] + bias);
    }
    {  // V head: v_t16[ch][n]
      f32x4 C = {0.f,0.f,0.f,0.f};
      #pragma unroll
      for(int kc=0; kc<4; ++kc){
        short8 bf = *(const short8*)(vw16 + (size_t)(nh*16 + c)*128 + kc*32 + qd*8);
        C = __builtin_amdgcn_mfma_f32_16x16x32_bf16(af[kc], bf, C, 0, 0, 0);
      }
      float bias = v_b[nh*16 + c];
      uint2 pk;
      pk.x = pack2(C[0]+bias, C[1]+bias);
      pk.y = pack2(C[2]+bias, C[3]+bias);
      *(uint2*)(v_t16 + hbase + (size_t)c*2048 + n0 + qd*4) = pk;
    }
  }
}

// ---------------------------------------------------------------- K2: MFMA flash attention, maxless log2 softmax
__global__ __launch_bounds__(256,3) void k_attn(
    const float* __restrict__ rws, const unsigned short* __restrict__ k_b16,
    const unsigned short* __restrict__ v_t16, const float* __restrict__ query,
    const unsigned* __restrict__ gP, float* __restrict__ attn_pc){
  __shared__ alignas(8) unsigned P32[47*258];   // 48,504 B rpe pair window
  __shared__ alignas(16) short p_sm[4][16*42];  // 5,376 B per-wave P^T (stride 42: no 4-way bank clash)
  int bx = blockIdx.x;            // 768 = vi*256 + bh*16 + mblk
  int vi = bx >> 8;
  int bh = (bx >> 4) & 15;
  int mblk = bx & 15;
  int b = bh >> 3, nh = bh & 7, g = nh >> 2, bg = b*2 + g;
  int tid = threadIdx.x, wid = tid >> 6;
  int lane = tid & 63, c = lane & 15, qd = lane >> 4;
  int m0 = mblk*64 + wid*16;
  // ---- window bounds (iy_lo in [-2, 17] -> window rows [iy_lo, iy_lo+46] inside gP's [-2,63])
  float gy0 = -1.f + (2.f/31.f)*(float)(mblk*2);
  float pyL = 15.5f*(gy0 - 4.f/3.f) + 31.f - 0.01f;
  float pyH = 15.5f*(gy0 + 2.f/31.f + 4.f/3.f) + 31.f + 0.01f;
  int a  = max(-1, (int)floorf(pyL));
  int bb = min(63, (int)floorf(pyH));
  int iy_lo = max(bb - 46, min(a - 1, 17));
  // ---- stage: flat uint2 memcpy from pre-paired global table
  {
    const uint2* src2 = (const uint2*)(gP + (size_t)nh*17028 + (size_t)(iy_lo+2)*258);
    uint2* dst2 = (uint2*)P32;
    for(int i = tid; i < 6063; i += 256) dst2[i] = src2[i];
  }
  short8 qa;
  #pragma unroll
  for(int j=0; j<8; ++j){
    int ch = qd*8 + j;
    qa[j] = (qd < 2) ? (short)f2b(query[(size_t)(b*128 + nh*16 + ch)*1024 + m0 + c]) : (short)0;
  }
  float Ax2[4], Ay2[4];
  #pragma unroll
  for(int r=0; r<4; ++r){
    int mr = m0 + qd*4 + r;
    float gxr = -1.f + (2.f/31.f)*(mr & 31);
    float gyr = -1.f + (2.f/31.f)*(mr >> 5);
    Ax2[r] = 63.5f*gxr + 128.f;
    Ay2[r] = 15.5f*gyr + 31.f - (float)iy_lo;
  }
  float loC = -1.f - (float)iy_lo, hiC = 63.f - (float)iy_lo;
  const float SC2 = 0.36067376022224085f;     // 0.25 * log2(e)
  float si[4] = {0.f, 0.f, 0.f, 0.f};
  f32x4 O = {0.f, 0.f, 0.f, 0.f};
  size_t kvb  = (size_t)(vi*16 + bh)*2048*16;
  size_t rwsb = (size_t)(vi*4 + bg)*2048;
  short* pw = &p_sm[wid][0];
  __syncthreads();                            // pair window ready (only barrier)
  for(int nc = 0; nc < 16; ++nc){
    int n0 = nc*128;
    const unsigned short* kbase = k_b16 + kvb + (size_t)n0*16;
    const unsigned short* vbase = v_t16 + kvb + (size_t)c*2048 + n0;
    const float* rbase = rws + (rwsb + n0)*2;
    #pragma unroll
    for(int hf = 0; hf < 4; ++hf){            // 32-n slice: 2 QK tiles + 1 PV
      f32x4 S[2];
      #pragma unroll
      for(int tt=0; tt<2; ++tt){
        short8 bk = {0,0,0,0,0,0,0,0};
        if(qd < 2) bk = *(const short8*)(kbase + (size_t)((hf*2+tt)*16 + c)*16 + qd*8);
        f32x4 z = {0.f,0.f,0.f,0.f};
        S[tt] = __builtin_amdgcn_mfma_f32_16x16x32_bf16(qa, bk, z, 0, 0, 0);
      }
      #pragma unroll
      for(int tt=0; tt<2; ++tt){
        float2 rs = *(const float2*)(rbase + ((hf*2+tt)*16 + c)*2);
        float ysc = rs.x, xsc = rs.y;         // 15.5*yn, 63.5*xn
        #pragma unroll
        for(int r=0; r<4; ++r){
          float px = Ax2[r] - xsc;
          float py = Ay2[r] - ysc;
          px = fminf(fmaxf(px, 0.f), 256.f);
          py = fminf(fmaxf(py, loC), hiC);
          float cf = floorf(px), rf = floorf(py);
          float fx = px - cf, fy = py - rf;
          int idx = (int)rf * 258 + (int)cf;
          unsigned w0 = P32[idx], w1 = P32[idx+1];
          float lo0 = __uint_as_float(w0 << 16), hi0 = __uint_as_float(w0 & 0xFFFF0000u);
          float lo1 = __uint_as_float(w1 << 16), hi1 = __uint_as_float(w1 & 0xFFFF0000u);
          float t0 = lo0 + fy*(hi0 - lo0);
          float t1 = lo1 + fy*(hi1 - lo1);
          float p = exp2f(S[tt][r]*SC2 + t0 + fx*(t1 - t0));
          si[r] += p;
          pw[(qd*4 + r)*42 + tt*16 + c] = (short)f2b(p);
        }
      }
      short8 va  = *(const short8*)(vbase + hf*32 + qd*8);
      short8 pbf = *(const short8*)(&pw[c*42 + qd*8]);
      O = __builtin_amdgcn_mfma_f32_16x16x32_bf16(va, pbf, O, 0, 0, 0);
    }
  }
  #pragma unroll
  for(int r=0; r<4; ++r){
    float sv = si[r];
    sv += __shfl_xor(sv, 1); sv += __shfl_xor(sv, 2);
    sv += __shfl_xor(sv, 4); sv += __shfl_xor(sv, 8);
    si[r] = sv;
  }
  int msrc = (c >> 2)*16 + c;
  int rsel = c & 3;
  float s0 = __shfl(si[0], msrc), s1 = __shfl(si[1], msrc),
        s2 = __shfl(si[2], msrc), s3 = __shfl(si[3], msrc);
  float sv = (rsel==0) ? s0 : ((rsel==1) ? s1 : ((rsel==2) ? s2 : s3));
  float inv = 1.f/sv;
  float4 o4;
  o4.x = O[0]*inv; o4.y = O[1]*inv; o4.z = O[2]*inv; o4.w = O[3]*inv;
  *(float4*)(attn_pc + (size_t)(b*1024 + m0 + c)*384 + vi*128 + nh*16 + qd*4) = o4;
}

// ---------------------------------------------------------------- K3: output projection (512 blocks, 2/CU)
__global__ __launch_bounds__(256) void k_outproj(
    const float* __restrict__ attn_pc, const float* __restrict__ ow_t, const float* __restrict__ out_b,
    float* __restrict__ out){
  __shared__ float A[4*384];         // 6 KB
  int bx = blockIdx.x;               // 512 = b*256 + mt
  int b  = bx >> 8;
  int m0 = (bx & 255)*4;
  const float4* src = (const float4*)(attn_pc + ((size_t)b*1024 + m0)*384);
  float4* dst = (float4*)A;
  for(int i = threadIdx.x; i < 384; i += 256) dst[i] = src[i];
  __syncthreads();
  int oc = threadIdx.x & 127;
  int mh = threadIdx.x >> 7;
  float acc[2] = {0.f, 0.f};
  for(int vc = 0; vc < 384; ++vc){
    float wv = ow_t[vc*128 + oc];
    #pragma unroll
    for(int j=0; j<2; ++j) acc[j] += wv * A[(mh*2+j)*384 + vc];
  }
  float ob = out_b[oc];
  #pragma unroll
  for(int j=0; j<2; ++j)
    out[((size_t)b*128 + oc)*1024 + m0 + mh*2 + j] = acc[j] + ob;
}

extern "C" void kernel_launch(void* const* d_in, const int* in_sizes, int n_in,
                              void* d_out, int out_size, void* d_ws, size_t ws_size,
                              hipStream_t stream){
  const float* x     = (const float*)d_in[0];
  const float* query = (const float*)d_in[1];
  const float* refp  = (const float*)d_in[2];
  const float* w1    = (const float*)d_in[3];
  const float* b1    = (const float*)d_in[4];
  const float* lng   = (const float*)d_in[5];
  const float* lnb   = (const float*)d_in[6];
  const float* w2    = (const float*)d_in[7];
  const float* k_w   = (const float*)d_in[8];
  const float* k_b   = (const float*)d_in[9];
  const float* v_w   = (const float*)d_in[10];
  const float* v_b   = (const float*)d_in[11];
  const float* out_w = (const float*)d_in[12];
  const float* out_b = (const float*)d_in[13];
  const float* rpe   = (const float*)d_in[14];

  const size_t O_XT   = 0;            // 12,582,912
  const size_t O_RWO  = 12582912;     //    196,608
  const size_t O_RWS  = 12779520;     //    196,608
  const size_t O_KB16 = 12976128;     //  3,145,728
  const size_t O_VT16 = 16121856;     //  3,145,728
  const size_t O_APC  = 19267584;     //  3,145,728
  const size_t O_KW16 = 22413312;     //     32,768
  const size_t O_VW16 = 22446080;     //     32,768
  const size_t O_OWT  = 22478848;     //    196,608
  const size_t O_GPT  = 22675456;     //    544,896 (gP pair table)
  const size_t NEED   = 23220352;
  if(ws_size < NEED){
    k_probe<<<1, 64, 0, stream>>>((float*)d_out, 100.f + (float)(ws_size >> 20));
    return;
  }
  char* ws = (char*)d_ws;
  float* xt      = (float*)(ws + O_XT);
  float* rwo     = (float*)(ws + O_RWO);
  float* rws     = (float*)(ws + O_RWS);
  unsigned short* k_b16 = (unsigned short*)(ws + O_KB16);
  unsigned short* v_t16 = (unsigned short*)(ws + O_VT16);
  float* attn_pc = (float*)(ws + O_APC);
  unsigned short* kw16 = (unsigned short*)(ws + O_KW16);
  unsigned short* vw16 = (unsigned short*)(ws + O_VW16);
  float* ow_t    = (float*)(ws + O_OWT);
  unsigned* gP   = (unsigned*)(ws + O_GPT);

  k_prep_off<<<4693, 256, 0, stream>>>(query, refp, w1, b1, lng, lnb, w2, rwo, rws,
                                       x, xt, k_w, v_w, out_w, kw16, vw16, ow_t, rpe, gP);
  k_sampro  <<<768,  256, 0, stream>>>(rwo, xt, kw16, k_b, vw16, v_b, k_b16, v_t16);
  k_attn    <<<768,  256, 0, stream>>>(rws, k_b16, v_t16, query, gP, attn_pc);
  k_outproj <<<512,  256, 0, stream>>>(attn_pc, ow_t, out_b, (float*)d_out);
}